// Round 22
// baseline (121.501 us; speedup 1.0000x reference)
//
#include <hip/hip_runtime.h>

#define B_ 16
#define C_ 256
#define N_ 2048
#define CK_ 64

using f32x4  = __attribute__((ext_vector_type(4))) float;
using bf16x8 = __attribute__((ext_vector_type(8))) short;
using short4_t = __attribute__((ext_vector_type(4))) short;
using u32x2  = __attribute__((ext_vector_type(2))) unsigned;

static __device__ __forceinline__ float bf2f(short s){
  unsigned u = ((unsigned)(unsigned short)s) << 16;
  float f; __builtin_memcpy(&f, &u, 4); return f;
}
static __device__ __forceinline__ short f2bf(float f){
  unsigned u; __builtin_memcpy(&u, &f, 4);
  unsigned r = (u + 0x7fffu + ((u >> 16) & 1u)) >> 16;   // RNE
  return (short)(unsigned short)r;
}

// XOR-swizzled byte offsets (128B pair-rows) for V tiles: bijective, DMA-linear image.
static __device__ __forceinline__ int vf_off(int cp, int ck){
  int q = cp >> 1; int ch = (((cp & 1) << 2) | ck) ^ (q & 7);
  return q*128 + ch*16;
}

// ---------------- K0: merged weights->bf16 + xsum (one launch).
__global__ void k_prep(const float* __restrict__ Wq, const float* __restrict__ Wk,
                       const float* __restrict__ Wv, const float* __restrict__ Wl,
                       short* __restrict__ Wb, short* __restrict__ Wlf,
                       const float* __restrict__ x, double* __restrict__ xsum){
  int bid = blockIdx.x;
  if(bid < 1024){
    int b = bid >> 6;
    int c = (bid & 63)*4 + (threadIdx.x>>6);
    int l = threadIdx.x & 63;
    const float* row = x + ((size_t)b*C_ + c)*N_;
    double s = 0.0;
    #pragma unroll
    for(int it = 0; it < 8; ++it){
      f32x4 v = *(const f32x4*)(row + it*256 + l*4);
      s += (double)v[0] + (double)v[1] + (double)v[2] + (double)v[3];
    }
    for(int off = 32; off; off >>= 1) s += __shfl_down(s, off);
    if(l == 0) xsum[b*C_ + c] = s;
  } else {
    int i = (bid - 1024)*256 + threadIdx.x;
    if(i < 384*C_){
      int o = i >> 8;
      float v;
      if(o < 64)       v = Wq[i];
      else if(o < 128) v = Wk[i - 64*C_];
      else             v = Wv[i - 128*C_];
      Wb[i] = f2bf(v);
    }
    if(i < C_*C_){
      int o = i >> 8, c = i & 255;
      int dest = (c>>5)*8192 + (o>>4)*512 + ((((c>>3)&3)*16) + (o&15))*8 + (c&7);
      Wlf[dest] = f2bf(Wl[i]);
    }
  }
}

// ---------------- K3: QKV projection; g computed in-block; 3 blocks/CU via
// LDS aliasing (xs/tg overlay csum2 -- dead before csum2's first write).
#define XROW 328
__global__ __launch_bounds__(256,3) void k_qkv(const float* __restrict__ x,
        const short* __restrict__ Wb, const double* __restrict__ xsum,
        const float* __restrict__ Wq, const float* __restrict__ Wk,
        short* __restrict__ qbuf, short* __restrict__ kf, short* __restrict__ vf,
        short* __restrict__ xTb){
  int b = blockIdx.y; int n0 = blockIdx.x*64;
  int tid = threadIdx.x, w = tid>>6, l = tid&63, lo = l&15, g = l>>4;
  __shared__ __attribute__((aligned(16))) short xT[64*XROW];   // 41 KB
  __shared__ double gs[C_];                                    // 2 KB
  __shared__ double csum2[256][4];                             // 8 KB (aliased below)
  __shared__ float inv_lds[64];                                // 256 B
  double* xs = (double*)&csum2[0][0];    // 2 KB alias (dead before csum2 writes)
  double* tg = (double*)&csum2[64][0];   // 512 B alias
  const float* xb = x + (size_t)b*C_*N_;
  // ---- in-block g = Wk^T (Wq xsum)
  xs[tid] = xsum[b*C_ + tid];
  __syncthreads();
  if(tid < CK_){
    double s = 0.0;
    const float* wr = Wq + (size_t)tid*C_;
    for(int c = 0; c < C_; ++c) s += (double)wr[c]*xs[c];
    tg[tid] = s;
  }
  __syncthreads();
  {
    double s = 0.0;
    for(int jq = 0; jq < CK_; ++jq) s += (double)Wk[(size_t)jq*C_ + tid]*tg[jq];
    gs[tid] = s;
  }
  __syncthreads();                       // xs/tg dead from here; csum2 may be written

  int pp2 = tid >> 4, cg = tid & 15;
  double cs[4] = {0.0, 0.0, 0.0, 0.0};
  #pragma unroll
  for(int cc = 0; cc < 8; ++cc){
    int ci = cc*32 + 2*pp2;
    f32x4 x0 = *(const f32x4*)(xb + (size_t)ci*N_ + n0 + 4*cg);
    f32x4 x1 = *(const f32x4*)(xb + (size_t)(ci+1)*N_ + n0 + 4*cg);
    #pragma unroll
    for(int jq = 0; jq < 4; ++jq){
      cs[jq] += (double)x0[jq]*gs[ci] + (double)x1[jq]*gs[ci+1];
      unsigned pr = (unsigned)(unsigned short)f2bf(x0[jq])
                  | (((unsigned)(unsigned short)f2bf(x1[jq]))<<16);
      *(unsigned*)(&xT[(4*cg + jq)*XROW + cc*40 + 2*pp2]) = pr;
    }
  }
  csum2[tid][0] = cs[0]; csum2[tid][1] = cs[1];
  csum2[tid][2] = cs[2]; csum2[tid][3] = cs[3];
  __syncthreads();                             // the ONE staging barrier
  if(tid < 64){
    int cgq = tid >> 2, jq = tid & 3;
    double tot = 0.0;
    #pragma unroll
    for(int k = 0; k < 16; ++k) tot += csum2[k*16 + cgq][jq];
    inv_lds[tid] = (float)(1.0/(1e-9 + tot));
  }

  f32x4 acc[6][4];
  #pragma unroll
  for(int oi=0;oi<6;++oi) for(int nj=0;nj<4;++nj) acc[oi][nj]=(f32x4){0.f,0.f,0.f,0.f};
  int n2 = tid>>2, ii2 = tid&3;
  short* xtb = xTb + ((size_t)b*N_ + n0)*C_;
  #pragma unroll
  for(int cc = 0; cc < 8; ++cc){
    *(bf16x8*)(xtb + (size_t)n2*C_ + cc*32 + 8*ii2) =
        *(const bf16x8*)(&xT[n2*XROW + cc*40 + 8*ii2]);
    bf16x8 bfr[4];
    #pragma unroll
    for(int nj = 0; nj < 4; ++nj)
      bfr[nj] = *(const bf16x8*)(&xT[(nj*16 + lo)*XROW + cc*40 + 8*g]);
    #pragma unroll
    for(int oi = 0; oi < 6; ++oi){
      int o = w*96 + oi*16 + lo;
      bf16x8 af = *(const bf16x8*)(Wb + (size_t)o*C_ + cc*32 + 8*g);
      #pragma unroll
      for(int nj = 0; nj < 4; ++nj)
        acc[oi][nj] = __builtin_amdgcn_mfma_f32_16x16x32_bf16(af, bfr[nj], acc[oi][nj], 0,0,0);
    }
  }
  __syncthreads();                             // inv_lds visible

  short* qb  = qbuf + (size_t)b*N_*64;
  short* kfb = kf   + (size_t)b*N_*64;
  short* vfb = vf   + (size_t)b*C_*N_;
  #pragma unroll
  for(int oi = 0; oi < 6; ++oi){
    int obase = w*96 + oi*16;
    for(int nj = 0; nj < 4; ++nj){
      int n = n0 + nj*16 + lo;
      if(obase < 64){                          // Q rows
        short4_t pk;
        #pragma unroll
        for(int r = 0; r < 4; ++r) pk[r] = f2bf(acc[oi][nj][r]);
        *(short4_t*)(qb + (size_t)n*64 + obase + 4*g) = pk;
      } else if(obase < 128){                  // K fragments
        int C0 = obase - 64 + 4*g;
        int mt = (n0>>4) + nj;
        int h  = C0 >> 5;
        int lanep = ((C0>>3)&3)*16 + lo;
        short4_t pk;
        #pragma unroll
        for(int r = 0; r < 4; ++r) pk[r] = f2bf(acc[oi][nj][r]);
        *(short4_t*)(kfb + ((size_t)(mt*2 + h)*64 + lanep)*8 + (C0&4)) = pk;
      } else {                                 // V pre-swizzled
        float iv = inv_lds[nj*16 + lo];
        int ckk = (n>>3)&3, wi = n&7, mc = n>>5;
        #pragma unroll
        for(int r = 0; r < 4; ++r){
          int cp = obase - 128 + 4*g + r;
          vfb[(size_t)mc*8192 + (vf_off(cp, ckk)>>1) + wi] = f2bf(acc[oi][nj][r]*iv);
        }
      }
    }
  }
}
#undef XROW

// ---------------- K4: attention + FUSED h-GEMM epilogue (r21, unchanged).
__global__ __launch_bounds__(256,2) void k_attn(const short* __restrict__ qbuf,
        const short* __restrict__ kf, const short* __restrict__ vf,
        const short* __restrict__ xTb, const short* __restrict__ Wlf,
        short* __restrict__ hT, float* __restrict__ part){
  int d = blockIdx.x;
  int xcd = d & 7, j = d >> 3;
  int b = xcd*2 + (j >> 5);
  int n0 = (j & 31)*64;
  int tid = threadIdx.x;
  int w = tid>>6, l = tid&63, lo = l&15, g = l>>4;

  __shared__ short vlds[2][16384];
  __shared__ short plds[4096];
  __shared__ float rs_lds[64];

  const short* qb  = qbuf + (size_t)b*N_*64;
  const short* kfb = kf   + (size_t)b*N_*64;
  const short* vfb = vf   + (size_t)b*C_*N_;

  bf16x8 qa0, qa1;
  {
    const short* qrow = qb + (size_t)(n0 + w*16 + lo)*64;
    qa0 = *(const bf16x8*)(qrow + 8*g);
    qa1 = *(const bf16x8*)(qrow + 32 + 8*g);
  }
  int paoff[4][2], bvoff[4][2], pw[4];
  #pragma unroll
  for(int rt = 0; rt < 4; ++rt)
    #pragma unroll
    for(int mh = 0; mh < 2; ++mh)
      paoff[rt][mh] = (rt*16 + lo)*128 + (((mh*4 + g) ^ (lo&7))*16);
  #pragma unroll
  for(int jj = 0; jj < 4; ++jj)
    #pragma unroll
    for(int mh = 0; mh < 2; ++mh)
      bvoff[jj][mh] = mh*16384 + vf_off(w*64 + jj*16 + lo, g);
  #pragma unroll
  for(int tt = 0; tt < 4; ++tt)
    pw[tt] = (w*16 + lo)*128 + (((tt*2 + (g>>1)) ^ (lo&7))*16) + (g&1)*8;

  const short* kl   = kfb + l*8;
  const short* vsrc = vfb + w*2048 + l*8;

  f32x4 oacc[4][4];                    // [jj (c-tiles)][rt (n-tiles)]
  #pragma unroll
  for(int jj=0;jj<4;++jj) for(int rt=0;rt<4;++rt) oacc[jj][rt]=(f32x4){0.f,0.f,0.f,0.f};
  float srow = 0.f;

  bf16x8 kA0,kA1,kA2,kA3,kA4,kA5,kA6,kA7;
  bf16x8 kB0,kB1,kB2,kB3,kB4,kB5,kB6,kB7;

#define LOADK(S, MC) { const short* kp = kl + (size_t)((MC)&31)*4096; \
    k##S##0 = *(const bf16x8*)(kp);        k##S##1 = *(const bf16x8*)(kp + 512); \
    k##S##2 = *(const bf16x8*)(kp + 1024); k##S##3 = *(const bf16x8*)(kp + 1536); \
    k##S##4 = *(const bf16x8*)(kp + 2048); k##S##5 = *(const bf16x8*)(kp + 2560); \
    k##S##6 = *(const bf16x8*)(kp + 3072); k##S##7 = *(const bf16x8*)(kp + 3584); }
#define GLLDS(SRC, DST) __builtin_amdgcn_global_load_lds( \
    (const __attribute__((address_space(1))) void*)(SRC), \
    (__attribute__((address_space(3))) void*)(DST), 16, 0, 0)
#define VDMA(MC, NB) { const short* vs = vsrc + (size_t)(2*(MC))*8192; \
    char* dst = (char*)&vlds[NB][0] + w*4096; \
    GLLDS(vs,        dst);        GLLDS(vs +  512, dst + 1024); \
    GLLDS(vs + 1024, dst + 2048); GLLDS(vs + 1536, dst + 3072); \
    GLLDS(vs + 8192,  dst + 16384); GLLDS(vs + 8704,  dst + 17408); \
    GLLDS(vs + 9216,  dst + 18432); GLLDS(vs + 9728,  dst + 19456); }
#define QKT(S, TT, KE, KO) { \
    f32x4 a = (f32x4){0.f,0.f,0.f,0.f}; \
    a = __builtin_amdgcn_mfma_f32_16x16x32_bf16(k##S##KE, qa0, a, 0,0,0); \
    a = __builtin_amdgcn_mfma_f32_16x16x32_bf16(k##S##KO, qa1, a, 0,0,0); \
    float e[4]; \
    _Pragma("unroll") \
    for(int r = 0; r < 4; ++r) e[r] = __builtin_exp2f(fmaf(a[r], 1.44269504f, -17.3123405f)); \
    srow += e[0]+e[1]+e[2]+e[3]; \
    unsigned p0, p1; \
    asm("v_cvt_pk_bf16_f32 %0, %1, %2" : "=v"(p0) : "v"(e[0]), "v"(e[1])); \
    asm("v_cvt_pk_bf16_f32 %0, %1, %2" : "=v"(p1) : "v"(e[2]), "v"(e[3])); \
    { u32x2 pv = {p0, p1}; *(u32x2*)((char*)&plds[0] + pw[TT]) = pv; } }

  LOADK(A, 0);
  LOADK(B, 1);
  VDMA(0, 0);

#define BODY(BUF, S, MC) { \
    VDMA(((MC)+1)&31, (BUF)^1); \
    QKT(S, 0, 0, 1); QKT(S, 1, 2, 3); QKT(S, 2, 4, 5); QKT(S, 3, 6, 7); \
    LOADK(S, (MC)+2); \
    __builtin_amdgcn_sched_barrier(0); \
    asm volatile("s_waitcnt vmcnt(16) lgkmcnt(0)" ::: "memory"); \
    __builtin_amdgcn_s_barrier(); \
    __builtin_amdgcn_sched_barrier(0); \
    __builtin_amdgcn_s_setprio(1); \
    _Pragma("unroll") \
    for(int mh = 0; mh < 2; ++mh){ \
      bf16x8 pa[4], bv[4]; \
      _Pragma("unroll") \
      for(int rt = 0; rt < 4; ++rt) pa[rt] = *(const bf16x8*)((char*)&plds[0] + paoff[rt][mh]); \
      _Pragma("unroll") \
      for(int jj = 0; jj < 4; ++jj) bv[jj] = *(const bf16x8*)((char*)&vlds[BUF][0] + bvoff[jj][mh]); \
      _Pragma("unroll") \
      for(int jj = 0; jj < 4; ++jj) \
        _Pragma("unroll") \
        for(int rt = 0; rt < 4; ++rt) \
          oacc[jj][rt] = __builtin_amdgcn_mfma_f32_16x16x32_bf16(bv[jj], pa[rt], oacc[jj][rt], 0,0,0); \
    } \
    __builtin_amdgcn_s_setprio(0); \
    __builtin_amdgcn_sched_barrier(0); \
    asm volatile("s_waitcnt lgkmcnt(0)" ::: "memory"); \
    __builtin_amdgcn_s_barrier(); \
    __builtin_amdgcn_sched_barrier(0); }

  #pragma unroll 1
  for(int it = 0; it < 16; ++it){
    BODY(0, A, 2*it);
    BODY(1, B, 2*it + 1);
  }
#undef BODY
#undef QKT
#undef VDMA
#undef GLLDS
#undef LOADK

  // row-sum completion
  float S = srow;
  S += __shfl_xor(S, 16);
  S += __shfl_xor(S, 32);
  if(l < 16) rs_lds[w*16 + l] = 1.f/(S + 1e-30f);
  asm volatile("s_waitcnt vmcnt(0)" ::: "memory");
  __syncthreads();
  float rinvn[4];
  #pragma unroll
  for(int rt = 0; rt < 4; ++rt) rinvn[rt] = rs_lds[rt*16 + lo];

  // ---- fused h-GEMM epilogue ----
  short* rT = (short*)&vlds[0][0];
  #pragma unroll
  for(int jj = 0; jj < 4; ++jj)
    #pragma unroll
    for(int rt = 0; rt < 4; ++rt){
      int nloc = rt*16 + lo;
      float e0 = oacc[jj][rt][0]*rinvn[rt], e1 = oacc[jj][rt][1]*rinvn[rt];
      float e2 = oacc[jj][rt][2]*rinvn[rt], e3 = oacc[jj][rt][3]*rinvn[rt];
      unsigned q0, q1;
      asm("v_cvt_pk_bf16_f32 %0, %1, %2" : "=v"(q0) : "v"(e0), "v"(e1));
      asm("v_cvt_pk_bf16_f32 %0, %1, %2" : "=v"(q1) : "v"(e2), "v"(e3));
      int cb8 = w*8 + jj*2 + (g>>1);
      int off = nloc*C_ + ((cb8 ^ (nloc&7))*8) + (g&1)*4;
      u32x2 pv = {q0, q1};
      *(u32x2*)(&rT[off]) = pv;
    }
  __syncthreads();
  {
    const short* xtb = xTb + ((size_t)b*N_ + n0)*C_;
    int half = l >> 5, ch = l & 31;
    #pragma unroll
    for(int k = 0; k < 8; ++k){
      int n = k*8 + w*2 + half;
      bf16x8 xv = *(const bf16x8*)(xtb + (size_t)n*C_ + ch*8);
      bf16x8* pr = (bf16x8*)(&rT[n*C_ + ((ch ^ (n&7))*8)]);
      bf16x8 av = *pr, rv;
      #pragma unroll
      for(int jq = 0; jq < 8; ++jq) rv[jq] = f2bf(bf2f(xv[jq]) - bf2f(av[jq]));
      *pr = rv;
    }
  }
  __syncthreads();
  f32x4 acc2[4][4];
  #pragma unroll
  for(int ot=0;ot<4;++ot) for(int nj=0;nj<4;++nj) acc2[ot][nj]=(f32x4){0.f,0.f,0.f,0.f};
  #pragma unroll
  for(int cb = 0; cb < 8; ++cb){
    bf16x8 bfr[4];
    #pragma unroll
    for(int nj = 0; nj < 4; ++nj)
      bfr[nj] = *(const bf16x8*)(&rT[(nj*16 + lo)*C_ + (((cb*4 + g) ^ (lo&7))*8)]);
    #pragma unroll
    for(int ot = 0; ot < 4; ++ot){
      bf16x8 af = *(const bf16x8*)(Wlf + ((size_t)(cb*16 + w*4 + ot))*512 + l*8);
      #pragma unroll
      for(int nj = 0; nj < 4; ++nj)
        acc2[ot][nj] = __builtin_amdgcn_mfma_f32_16x16x32_bf16(af, bfr[nj], acc2[ot][nj], 0,0,0);
    }
  }
  int bid = b*32 + (n0 >> 6);
  float* pr_ = part + (size_t)bid*512;
  #pragma unroll
  for(int ot = 0; ot < 4; ++ot){
    float s4[4] = {0,0,0,0}, q4[4] = {0,0,0,0};
    for(int nj = 0; nj < 4; ++nj)
      #pragma unroll
      for(int r = 0; r < 4; ++r){ float v = acc2[ot][nj][r]; s4[r] += v; q4[r] += v*v; }
    #pragma unroll
    for(int r = 0; r < 4; ++r){
      float ss = s4[r], qq = q4[r];
      for(int msk = 1; msk < 16; msk <<= 1){ ss += __shfl_xor(ss, msk); qq += __shfl_xor(qq, msk); }
      if(lo == 0){
        int o = w*64 + ot*16 + 4*g + r;
        pr_[o] = ss;
        pr_[256 + o] = qq;
      }
    }
  }
  short* tT = (short*)&vlds[1][0];
  #pragma unroll
  for(int ot = 0; ot < 4; ++ot)
    #pragma unroll
    for(int nj = 0; nj < 4; ++nj)
      #pragma unroll
      for(int r = 0; r < 4; ++r){
        int o = w*64 + ot*16 + 4*g + r;
        int n = nj*16 + lo;
        tT[o*64 + (n ^ (((o>>2)&3)*16))] = f2bf(acc2[ot][nj][r]);
      }
  __syncthreads();
  short* hTb = hT + (size_t)b*C_*N_ + n0;
  {
    int ro = tid >> 3, li = tid & 7;
    #pragma unroll
    for(int pss = 0; pss < 8; ++pss){
      int o = pss*32 + ro;
      bf16x8 v = *(const bf16x8*)(&tT[o*64 + ((li*8) ^ (((o>>2)&3)*16))]);
      *(bf16x8*)(hTb + (size_t)o*N_ + li*8) = v;
    }
  }
}

// ---------------- K6a: BN partial reduce stage A (64 blocks, coalesced rows)
__global__ void k_bnred(const float* __restrict__ part, float* __restrict__ part2){
  int j = blockIdx.x;
  int t = threadIdx.x;
  float s0 = 0.f, s1 = 0.f;
  #pragma unroll
  for(int r = 0; r < 8; ++r){
    const float* pr_ = part + (size_t)(j*8 + r)*512;
    s0 += pr_[t];
    s1 += pr_[t + 256];
  }
  part2[(size_t)j*512 + t] = s0;
  part2[(size_t)j*512 + t + 256] = s1;
}

// ---------------- K6b: BN reduce (64 partial rows) + finalize scale/shift
__global__ void k_bnfin(const float* __restrict__ part2,
                        const float* __restrict__ gamma, const float* __restrict__ beta,
                        float* __restrict__ bnsc, float* __restrict__ bnsh){
  __shared__ float ls[4][512];
  int t = threadIdx.x; int o = t & 255, seg = t >> 8;
  float s = 0.f, q = 0.f;
  for(int r = seg*16; r < seg*16 + 16; ++r){
    s += part2[(size_t)r*512 + o];
    q += part2[(size_t)r*512 + 256 + o];
  }
  ls[seg][o] = s; ls[seg][256 + o] = q;
  __syncthreads();
  if(t < 256){
    float S = ls[0][t] + ls[1][t] + ls[2][t] + ls[3][t];
    float Q = ls[0][256+t] + ls[1][256+t] + ls[2][256+t] + ls[3][256+t];
    float cnt = (float)(B_*N_);
    float mean = S/cnt;
    float var  = Q/cnt - mean*mean;
    float is   = rsqrtf(var + 1e-5f);
    float sc   = gamma[t]*is;
    bnsc[t] = sc;
    bnsh[t] = beta[t] - mean*sc;
  }
}

// ---------------- K7: streaming out[c][n] = x + relu(hT*sc+sh). No LDS, no barrier.
__global__ void k_final(const float* __restrict__ x, const short* __restrict__ hT,
                        const float* __restrict__ bnsc, const float* __restrict__ bnsh,
                        float* __restrict__ out){
  int row = blockIdx.x;
  int c = row & 255;
  float sc = bnsc[c], sh = bnsh[c];
  const short* hr = hT + (size_t)row*N_;
  const float* xr = x + (size_t)row*N_;
  float* orow = out + (size_t)row*N_;
  int t = threadIdx.x;
  bf16x8 hv = *(const bf16x8*)(hr + t*8);
  f32x4 x0 = *(const f32x4*)(xr + t*8);
  f32x4 x1 = *(const f32x4*)(xr + t*8 + 4);
  f32x4 o0, o1;
  #pragma unroll
  for(int jq = 0; jq < 4; ++jq){
    o0[jq] = x0[jq] + fmaxf(fmaf(bf2f(hv[jq]), sc, sh), 0.f);
    o1[jq] = x1[jq] + fmaxf(fmaf(bf2f(hv[jq+4]), sc, sh), 0.f);
  }
  *(f32x4*)(orow + t*8) = o0;
  *(f32x4*)(orow + t*8 + 4) = o1;
}

extern "C" void kernel_launch(void* const* d_in, const int* in_sizes, int n_in,
                              void* d_out, int out_size, void* d_ws, size_t ws_size,
                              hipStream_t stream){
  const float* x     = (const float*)d_in[0];
  const float* Wq    = (const float*)d_in[1];
  const float* Wk    = (const float*)d_in[2];
  const float* Wv    = (const float*)d_in[3];
  const float* Wl    = (const float*)d_in[4];
  const float* gamma = (const float*)d_in[5];
  const float* beta  = (const float*)d_in[6];
  float* out = (float*)d_out;

  char* p = (char*)d_ws;
  double* xsum = (double*)p; p += (size_t)B_*C_*8;
  short* Wb   = (short*)p;  p += (size_t)384*C_*2;
  short* Wlf  = (short*)p;  p += (size_t)C_*C_*2;
  short* qbuf = (short*)p;  p += (size_t)B_*N_*64*2;
  short* kf   = (short*)p;  p += (size_t)B_*N_*64*2;
  short* vf   = (short*)p;  p += (size_t)B_*C_*N_*2;
  short* xTb  = (short*)p;  p += (size_t)B_*N_*C_*2;
  short* hT   = (short*)p;  p += (size_t)B_*N_*C_*2;
  float* part = (float*)p;  p += (size_t)512*512*4;
  float* part2= (float*)p;  p += (size_t)64*512*4;
  float* bnsc = (float*)p;  p += C_*4;
  float* bnsh = (float*)p;  p += C_*4;

  k_prep  <<<1408, 256, 0, stream>>>(Wq, Wk, Wv, Wl, Wb, Wlf, x, xsum);
  k_qkv   <<<dim3(N_/64, B_), 256, 0, stream>>>(x, Wb, xsum, Wq, Wk, qbuf, kf, vf, xTb);
  k_attn  <<<512, 256, 0, stream>>>(qbuf, kf, vf, xTb, Wlf, hT, part);
  k_bnred <<<64, 256, 0, stream>>>(part, part2);
  k_bnfin <<<1, 1024, 0, stream>>>(part2, gamma, beta, bnsc, bnsh);
  k_final <<<4096, 256, 0, stream>>>(x, hT, bnsc, bnsh, out);
}

// Round 23
// 119.904 us; speedup vs baseline: 1.0133x; 1.0133x over previous
//
#include <hip/hip_runtime.h>

#define B_ 16
#define C_ 256
#define N_ 2048
#define CK_ 64

using f32x4  = __attribute__((ext_vector_type(4))) float;
using bf16x8 = __attribute__((ext_vector_type(8))) short;
using short4_t = __attribute__((ext_vector_type(4))) short;
using u32x2  = __attribute__((ext_vector_type(2))) unsigned;

static __device__ __forceinline__ float bf2f(short s){
  unsigned u = ((unsigned)(unsigned short)s) << 16;
  float f; __builtin_memcpy(&f, &u, 4); return f;
}
static __device__ __forceinline__ short f2bf(float f){
  unsigned u; __builtin_memcpy(&u, &f, 4);
  unsigned r = (u + 0x7fffu + ((u >> 16) & 1u)) >> 16;   // RNE
  return (short)(unsigned short)r;
}

// XOR-swizzled byte offsets (128B pair-rows) for V tiles: bijective, DMA-linear image.
static __device__ __forceinline__ int vf_off(int cp, int ck){
  int q = cp >> 1; int ch = (((cp & 1) << 2) | ck) ^ (q & 7);
  return q*128 + ch*16;
}

// ---------------- K0: merged weights->bf16 + xsum (one launch).
__global__ void k_prep(const float* __restrict__ Wq, const float* __restrict__ Wk,
                       const float* __restrict__ Wv, const float* __restrict__ Wl,
                       short* __restrict__ Wb, short* __restrict__ Wlf,
                       const float* __restrict__ x, double* __restrict__ xsum){
  int bid = blockIdx.x;
  if(bid < 1024){
    int b = bid >> 6;
    int c = (bid & 63)*4 + (threadIdx.x>>6);
    int l = threadIdx.x & 63;
    const float* row = x + ((size_t)b*C_ + c)*N_;
    double s = 0.0;
    #pragma unroll
    for(int it = 0; it < 8; ++it){
      f32x4 v = *(const f32x4*)(row + it*256 + l*4);
      s += (double)v[0] + (double)v[1] + (double)v[2] + (double)v[3];
    }
    for(int off = 32; off; off >>= 1) s += __shfl_down(s, off);
    if(l == 0) xsum[b*C_ + c] = s;
  } else {
    int i = (bid - 1024)*256 + threadIdx.x;
    if(i < 384*C_){
      int o = i >> 8;
      float v;
      if(o < 64)       v = Wq[i];
      else if(o < 128) v = Wk[i - 64*C_];
      else             v = Wv[i - 128*C_];
      Wb[i] = f2bf(v);
    }
    if(i < C_*C_){
      int o = i >> 8, c = i & 255;
      int dest = (c>>5)*8192 + (o>>4)*512 + ((((c>>3)&3)*16) + (o&15))*8 + (c&7);
      Wlf[dest] = f2bf(Wl[i]);
    }
  }
}

// ---------------- K3: QKV projection; g computed in-block (f64, identical order
// in every block -> deterministic), colsum fused; stage-once/compute-once.
#define XROW 328
__global__ __launch_bounds__(256,2) void k_qkv(const float* __restrict__ x,
        const short* __restrict__ Wb, const double* __restrict__ xsum,
        const float* __restrict__ Wq, const float* __restrict__ Wk,
        short* __restrict__ qbuf, short* __restrict__ kf, short* __restrict__ vf,
        short* __restrict__ xTb){
  int b = blockIdx.y; int n0 = blockIdx.x*64;
  int tid = threadIdx.x, w = tid>>6, l = tid&63, lo = l&15, g = l>>4;
  __shared__ __attribute__((aligned(16))) short xT[64*XROW];   // 41 KB
  __shared__ double gs[C_];
  __shared__ double xs[C_];
  __shared__ double tg[CK_];
  __shared__ double csum2[256][4];                             // 8 KB
  __shared__ float inv_lds[64];
  const float* xb = x + (size_t)b*C_*N_;
  // ---- in-block g = Wk^T (Wq xsum)
  xs[tid] = xsum[b*C_ + tid];
  __syncthreads();
  if(tid < CK_){
    double s = 0.0;
    const float* wr = Wq + (size_t)tid*C_;
    for(int c = 0; c < C_; ++c) s += (double)wr[c]*xs[c];
    tg[tid] = s;
  }
  __syncthreads();
  {
    double s = 0.0;
    for(int jq = 0; jq < CK_; ++jq) s += (double)Wk[(size_t)jq*C_ + tid]*tg[jq];
    gs[tid] = s;
  }
  __syncthreads();

  int pp2 = tid >> 4, cg = tid & 15;
  double cs[4] = {0.0, 0.0, 0.0, 0.0};
  #pragma unroll
  for(int cc = 0; cc < 8; ++cc){
    int ci = cc*32 + 2*pp2;
    f32x4 x0 = *(const f32x4*)(xb + (size_t)ci*N_ + n0 + 4*cg);
    f32x4 x1 = *(const f32x4*)(xb + (size_t)(ci+1)*N_ + n0 + 4*cg);
    #pragma unroll
    for(int jq = 0; jq < 4; ++jq){
      cs[jq] += (double)x0[jq]*gs[ci] + (double)x1[jq]*gs[ci+1];
      unsigned pr = (unsigned)(unsigned short)f2bf(x0[jq])
                  | (((unsigned)(unsigned short)f2bf(x1[jq]))<<16);
      *(unsigned*)(&xT[(4*cg + jq)*XROW + cc*40 + 2*pp2]) = pr;
    }
  }
  csum2[tid][0] = cs[0]; csum2[tid][1] = cs[1];
  csum2[tid][2] = cs[2]; csum2[tid][3] = cs[3];
  __syncthreads();                             // the ONE staging barrier
  if(tid < 64){
    int cgq = tid >> 2, jq = tid & 3;
    double tot = 0.0;
    #pragma unroll
    for(int k = 0; k < 16; ++k) tot += csum2[k*16 + cgq][jq];
    inv_lds[tid] = (float)(1.0/(1e-9 + tot));
  }

  f32x4 acc[6][4];
  #pragma unroll
  for(int oi=0;oi<6;++oi) for(int nj=0;nj<4;++nj) acc[oi][nj]=(f32x4){0.f,0.f,0.f,0.f};
  int n2 = tid>>2, ii2 = tid&3;
  short* xtb = xTb + ((size_t)b*N_ + n0)*C_;
  #pragma unroll
  for(int cc = 0; cc < 8; ++cc){
    *(bf16x8*)(xtb + (size_t)n2*C_ + cc*32 + 8*ii2) =
        *(const bf16x8*)(&xT[n2*XROW + cc*40 + 8*ii2]);
    bf16x8 bfr[4];
    #pragma unroll
    for(int nj = 0; nj < 4; ++nj)
      bfr[nj] = *(const bf16x8*)(&xT[(nj*16 + lo)*XROW + cc*40 + 8*g]);
    #pragma unroll
    for(int oi = 0; oi < 6; ++oi){
      int o = w*96 + oi*16 + lo;
      bf16x8 af = *(const bf16x8*)(Wb + (size_t)o*C_ + cc*32 + 8*g);
      #pragma unroll
      for(int nj = 0; nj < 4; ++nj)
        acc[oi][nj] = __builtin_amdgcn_mfma_f32_16x16x32_bf16(af, bfr[nj], acc[oi][nj], 0,0,0);
    }
  }
  __syncthreads();                             // inv_lds visible

  short* qb  = qbuf + (size_t)b*N_*64;
  short* kfb = kf   + (size_t)b*N_*64;
  short* vfb = vf   + (size_t)b*C_*N_;
  #pragma unroll
  for(int oi = 0; oi < 6; ++oi){
    int obase = w*96 + oi*16;
    for(int nj = 0; nj < 4; ++nj){
      int n = n0 + nj*16 + lo;
      if(obase < 64){                          // Q rows
        short4_t pk;
        #pragma unroll
        for(int r = 0; r < 4; ++r) pk[r] = f2bf(acc[oi][nj][r]);
        *(short4_t*)(qb + (size_t)n*64 + obase + 4*g) = pk;
      } else if(obase < 128){                  // K fragments
        int C0 = obase - 64 + 4*g;
        int mt = (n0>>4) + nj;
        int h  = C0 >> 5;
        int lanep = ((C0>>3)&3)*16 + lo;
        short4_t pk;
        #pragma unroll
        for(int r = 0; r < 4; ++r) pk[r] = f2bf(acc[oi][nj][r]);
        *(short4_t*)(kfb + ((size_t)(mt*2 + h)*64 + lanep)*8 + (C0&4)) = pk;
      } else {                                 // V pre-swizzled
        float iv = inv_lds[nj*16 + lo];
        int ckk = (n>>3)&3, wi = n&7, mc = n>>5;
        #pragma unroll
        for(int r = 0; r < 4; ++r){
          int cp = obase - 128 + 4*g + r;
          vfb[(size_t)mc*8192 + (vf_off(cp, ckk)>>1) + wi] = f2bf(acc[oi][nj][r]*iv);
        }
      }
    }
  }
}
#undef XROW

// ---------------- K4: attention + FUSED h-GEMM epilogue. PV operands SWAPPED:
// oacc[jj][rt] has c on regs, n on lanes -> scalar rinv per lane, packed b64
// scatter into the r-tile.
__global__ __launch_bounds__(256,2) void k_attn(const short* __restrict__ qbuf,
        const short* __restrict__ kf, const short* __restrict__ vf,
        const short* __restrict__ xTb, const short* __restrict__ Wlf,
        short* __restrict__ hT, float* __restrict__ part){
  int d = blockIdx.x;
  int xcd = d & 7, j = d >> 3;
  int b = xcd*2 + (j >> 5);
  int n0 = (j & 31)*64;
  int tid = threadIdx.x;
  int w = tid>>6, l = tid&63, lo = l&15, g = l>>4;

  __shared__ short vlds[2][16384];
  __shared__ short plds[4096];
  __shared__ float rs_lds[64];

  const short* qb  = qbuf + (size_t)b*N_*64;
  const short* kfb = kf   + (size_t)b*N_*64;
  const short* vfb = vf   + (size_t)b*C_*N_;

  bf16x8 qa0, qa1;
  {
    const short* qrow = qb + (size_t)(n0 + w*16 + lo)*64;
    qa0 = *(const bf16x8*)(qrow + 8*g);
    qa1 = *(const bf16x8*)(qrow + 32 + 8*g);
  }
  int paoff[4][2], bvoff[4][2], pw[4];
  #pragma unroll
  for(int rt = 0; rt < 4; ++rt)
    #pragma unroll
    for(int mh = 0; mh < 2; ++mh)
      paoff[rt][mh] = (rt*16 + lo)*128 + (((mh*4 + g) ^ (lo&7))*16);
  #pragma unroll
  for(int jj = 0; jj < 4; ++jj)
    #pragma unroll
    for(int mh = 0; mh < 2; ++mh)
      bvoff[jj][mh] = mh*16384 + vf_off(w*64 + jj*16 + lo, g);
  #pragma unroll
  for(int tt = 0; tt < 4; ++tt)
    pw[tt] = (w*16 + lo)*128 + (((tt*2 + (g>>1)) ^ (lo&7))*16) + (g&1)*8;

  const short* kl   = kfb + l*8;
  const short* vsrc = vfb + w*2048 + l*8;

  f32x4 oacc[4][4];                    // [jj (c-tiles)][rt (n-tiles)]
  #pragma unroll
  for(int jj=0;jj<4;++jj) for(int rt=0;rt<4;++rt) oacc[jj][rt]=(f32x4){0.f,0.f,0.f,0.f};
  float srow = 0.f;

  bf16x8 kA0,kA1,kA2,kA3,kA4,kA5,kA6,kA7;
  bf16x8 kB0,kB1,kB2,kB3,kB4,kB5,kB6,kB7;

#define LOADK(S, MC) { const short* kp = kl + (size_t)((MC)&31)*4096; \
    k##S##0 = *(const bf16x8*)(kp);        k##S##1 = *(const bf16x8*)(kp + 512); \
    k##S##2 = *(const bf16x8*)(kp + 1024); k##S##3 = *(const bf16x8*)(kp + 1536); \
    k##S##4 = *(const bf16x8*)(kp + 2048); k##S##5 = *(const bf16x8*)(kp + 2560); \
    k##S##6 = *(const bf16x8*)(kp + 3072); k##S##7 = *(const bf16x8*)(kp + 3584); }
#define GLLDS(SRC, DST) __builtin_amdgcn_global_load_lds( \
    (const __attribute__((address_space(1))) void*)(SRC), \
    (__attribute__((address_space(3))) void*)(DST), 16, 0, 0)
#define VDMA(MC, NB) { const short* vs = vsrc + (size_t)(2*(MC))*8192; \
    char* dst = (char*)&vlds[NB][0] + w*4096; \
    GLLDS(vs,        dst);        GLLDS(vs +  512, dst + 1024); \
    GLLDS(vs + 1024, dst + 2048); GLLDS(vs + 1536, dst + 3072); \
    GLLDS(vs + 8192,  dst + 16384); GLLDS(vs + 8704,  dst + 17408); \
    GLLDS(vs + 9216,  dst + 18432); GLLDS(vs + 9728,  dst + 19456); }
#define QKT(S, TT, KE, KO) { \
    f32x4 a = (f32x4){0.f,0.f,0.f,0.f}; \
    a = __builtin_amdgcn_mfma_f32_16x16x32_bf16(k##S##KE, qa0, a, 0,0,0); \
    a = __builtin_amdgcn_mfma_f32_16x16x32_bf16(k##S##KO, qa1, a, 0,0,0); \
    float e[4]; \
    _Pragma("unroll") \
    for(int r = 0; r < 4; ++r) e[r] = __builtin_exp2f(fmaf(a[r], 1.44269504f, -17.3123405f)); \
    srow += e[0]+e[1]+e[2]+e[3]; \
    unsigned p0, p1; \
    asm("v_cvt_pk_bf16_f32 %0, %1, %2" : "=v"(p0) : "v"(e[0]), "v"(e[1])); \
    asm("v_cvt_pk_bf16_f32 %0, %1, %2" : "=v"(p1) : "v"(e[2]), "v"(e[3])); \
    { u32x2 pv = {p0, p1}; *(u32x2*)((char*)&plds[0] + pw[TT]) = pv; } }

  LOADK(A, 0);
  LOADK(B, 1);
  VDMA(0, 0);

#define BODY(BUF, S, MC) { \
    VDMA(((MC)+1)&31, (BUF)^1); \
    QKT(S, 0, 0, 1); QKT(S, 1, 2, 3); QKT(S, 2, 4, 5); QKT(S, 3, 6, 7); \
    LOADK(S, (MC)+2); \
    __builtin_amdgcn_sched_barrier(0); \
    asm volatile("s_waitcnt vmcnt(16) lgkmcnt(0)" ::: "memory"); \
    __builtin_amdgcn_s_barrier(); \
    __builtin_amdgcn_sched_barrier(0); \
    __builtin_amdgcn_s_setprio(1); \
    _Pragma("unroll") \
    for(int mh = 0; mh < 2; ++mh){ \
      bf16x8 pa[4], bv[4]; \
      _Pragma("unroll") \
      for(int rt = 0; rt < 4; ++rt) pa[rt] = *(const bf16x8*)((char*)&plds[0] + paoff[rt][mh]); \
      _Pragma("unroll") \
      for(int jj = 0; jj < 4; ++jj) bv[jj] = *(const bf16x8*)((char*)&vlds[BUF][0] + bvoff[jj][mh]); \
      _Pragma("unroll") \
      for(int jj = 0; jj < 4; ++jj) \
        _Pragma("unroll") \
        for(int rt = 0; rt < 4; ++rt) \
          oacc[jj][rt] = __builtin_amdgcn_mfma_f32_16x16x32_bf16(bv[jj], pa[rt], oacc[jj][rt], 0,0,0); \
    } \
    __builtin_amdgcn_s_setprio(0); \
    __builtin_amdgcn_sched_barrier(0); \
    asm volatile("s_waitcnt lgkmcnt(0)" ::: "memory"); \
    __builtin_amdgcn_s_barrier(); \
    __builtin_amdgcn_sched_barrier(0); }

  #pragma unroll 1
  for(int it = 0; it < 16; ++it){
    BODY(0, A, 2*it);
    BODY(1, B, 2*it + 1);
  }
#undef BODY
#undef QKT
#undef VDMA
#undef GLLDS
#undef LOADK

  // row-sum completion
  float S = srow;
  S += __shfl_xor(S, 16);
  S += __shfl_xor(S, 32);
  if(l < 16) rs_lds[w*16 + l] = 1.f/(S + 1e-30f);
  // drain the final body's in-flight VDMA (targets vlds[0], reused as r-tile below)
  asm volatile("s_waitcnt vmcnt(0)" ::: "memory");
  __syncthreads();
  float rinvn[4];
  #pragma unroll
  for(int rt = 0; rt < 4; ++rt) rinvn[rt] = rs_lds[rt*16 + lo];

  // ---- fused h-GEMM epilogue ----
  short* rT = (short*)&vlds[0][0];       // 32KB [64 n][256 c], chunk-swizzled
  // Pass A: packed b64 scatter of att*rinv (c on regs: 4 consecutive c per quad)
  #pragma unroll
  for(int jj = 0; jj < 4; ++jj)
    #pragma unroll
    for(int rt = 0; rt < 4; ++rt){
      int nloc = rt*16 + lo;
      float e0 = oacc[jj][rt][0]*rinvn[rt], e1 = oacc[jj][rt][1]*rinvn[rt];
      float e2 = oacc[jj][rt][2]*rinvn[rt], e3 = oacc[jj][rt][3]*rinvn[rt];
      unsigned q0, q1;
      asm("v_cvt_pk_bf16_f32 %0, %1, %2" : "=v"(q0) : "v"(e0), "v"(e1));
      asm("v_cvt_pk_bf16_f32 %0, %1, %2" : "=v"(q1) : "v"(e2), "v"(e3));
      int cb8 = w*8 + jj*2 + (g>>1);     // c>>3
      int off = nloc*C_ + ((cb8 ^ (nloc&7))*8) + (g&1)*4;
      u32x2 pv = {q0, q1};
      *(u32x2*)(&rT[off]) = pv;
    }
  __syncthreads();
  // Pass B: r = xT - att (b128 RMW, coalesced xTb reads)
  {
    const short* xtb = xTb + ((size_t)b*N_ + n0)*C_;
    int half = l >> 5, ch = l & 31;
    #pragma unroll
    for(int k = 0; k < 8; ++k){
      int n = k*8 + w*2 + half;
      bf16x8 xv = *(const bf16x8*)(xtb + (size_t)n*C_ + ch*8);
      bf16x8* pr = (bf16x8*)(&rT[n*C_ + ((ch ^ (n&7))*8)]);
      bf16x8 av = *pr, rv;
      #pragma unroll
      for(int jq = 0; jq < 8; ++jq) rv[jq] = f2bf(bf2f(xv[jq]) - bf2f(av[jq]));
      *pr = rv;
    }
  }
  __syncthreads();
  // Wl GEMM (k_hgemm body)
  f32x4 acc2[4][4];
  #pragma unroll
  for(int ot=0;ot<4;++ot) for(int nj=0;nj<4;++nj) acc2[ot][nj]=(f32x4){0.f,0.f,0.f,0.f};
  #pragma unroll
  for(int cb = 0; cb < 8; ++cb){
    bf16x8 bfr[4];
    #pragma unroll
    for(int nj = 0; nj < 4; ++nj)
      bfr[nj] = *(const bf16x8*)(&rT[(nj*16 + lo)*C_ + (((cb*4 + g) ^ (lo&7))*8)]);
    #pragma unroll
    for(int ot = 0; ot < 4; ++ot){
      bf16x8 af = *(const bf16x8*)(Wlf + ((size_t)(cb*16 + w*4 + ot))*512 + l*8);
      #pragma unroll
      for(int nj = 0; nj < 4; ++nj)
        acc2[ot][nj] = __builtin_amdgcn_mfma_f32_16x16x32_bf16(af, bfr[nj], acc2[ot][nj], 0,0,0);
    }
  }
  // BN partials (no atomics; disjoint per-wave channel ranges)
  int bid = b*32 + (n0 >> 6);
  float* pr_ = part + (size_t)bid*512;
  #pragma unroll
  for(int ot = 0; ot < 4; ++ot){
    float s4[4] = {0,0,0,0}, q4[4] = {0,0,0,0};
    for(int nj = 0; nj < 4; ++nj)
      #pragma unroll
      for(int r = 0; r < 4; ++r){ float v = acc2[ot][nj][r]; s4[r] += v; q4[r] += v*v; }
    #pragma unroll
    for(int r = 0; r < 4; ++r){
      float ss = s4[r], qq = q4[r];
      for(int msk = 1; msk < 16; msk <<= 1){ ss += __shfl_xor(ss, msk); qq += __shfl_xor(qq, msk); }
      if(lo == 0){
        int o = w*64 + ot*16 + 4*g + r;
        pr_[o] = ss;
        pr_[256 + o] = qq;
      }
    }
  }
  // transpose h via vlds[1], then coalesced hT write
  short* tT = (short*)&vlds[1][0];
  #pragma unroll
  for(int ot = 0; ot < 4; ++ot)
    #pragma unroll
    for(int nj = 0; nj < 4; ++nj)
      #pragma unroll
      for(int r = 0; r < 4; ++r){
        int o = w*64 + ot*16 + 4*g + r;
        int n = nj*16 + lo;
        tT[o*64 + (n ^ (((o>>2)&3)*16))] = f2bf(acc2[ot][nj][r]);
      }
  __syncthreads();
  short* hTb = hT + (size_t)b*C_*N_ + n0;
  {
    int ro = tid >> 3, li = tid & 7;
    #pragma unroll
    for(int pss = 0; pss < 8; ++pss){
      int o = pss*32 + ro;
      bf16x8 v = *(const bf16x8*)(&tT[o*64 + ((li*8) ^ (((o>>2)&3)*16))]);
      *(bf16x8*)(hTb + (size_t)o*N_ + li*8) = v;
    }
  }
}

// ---------------- K6a: BN partial reduce stage A (64 blocks, coalesced rows)
__global__ void k_bnred(const float* __restrict__ part, float* __restrict__ part2){
  int j = blockIdx.x;
  int t = threadIdx.x;
  float s0 = 0.f, s1 = 0.f;
  #pragma unroll
  for(int r = 0; r < 8; ++r){
    const float* pr_ = part + (size_t)(j*8 + r)*512;
    s0 += pr_[t];
    s1 += pr_[t + 256];
  }
  part2[(size_t)j*512 + t] = s0;
  part2[(size_t)j*512 + t + 256] = s1;
}

// ---------------- K6b: BN reduce (64 partial rows) + finalize scale/shift
__global__ void k_bnfin(const float* __restrict__ part2,
                        const float* __restrict__ gamma, const float* __restrict__ beta,
                        float* __restrict__ bnsc, float* __restrict__ bnsh){
  __shared__ float ls[4][512];
  int t = threadIdx.x; int o = t & 255, seg = t >> 8;
  float s = 0.f, q = 0.f;
  for(int r = seg*16; r < seg*16 + 16; ++r){
    s += part2[(size_t)r*512 + o];
    q += part2[(size_t)r*512 + 256 + o];
  }
  ls[seg][o] = s; ls[seg][256 + o] = q;
  __syncthreads();
  if(t < 256){
    float S = ls[0][t] + ls[1][t] + ls[2][t] + ls[3][t];
    float Q = ls[0][256+t] + ls[1][256+t] + ls[2][256+t] + ls[3][256+t];
    float cnt = (float)(B_*N_);
    float mean = S/cnt;
    float var  = Q/cnt - mean*mean;
    float is   = rsqrtf(var + 1e-5f);
    float sc   = gamma[t]*is;
    bnsc[t] = sc;
    bnsh[t] = beta[t] - mean*sc;
  }
}

// ---------------- K7: streaming out[c][n] = x + relu(hT*sc+sh). No LDS, no barrier.
__global__ void k_final(const float* __restrict__ x, const short* __restrict__ hT,
                        const float* __restrict__ bnsc, const float* __restrict__ bnsh,
                        float* __restrict__ out){
  int row = blockIdx.x;
  int c = row & 255;
  float sc = bnsc[c], sh = bnsh[c];
  const short* hr = hT + (size_t)row*N_;
  const float* xr = x + (size_t)row*N_;
  float* orow = out + (size_t)row*N_;
  int t = threadIdx.x;
  bf16x8 hv = *(const bf16x8*)(hr + t*8);
  f32x4 x0 = *(const f32x4*)(xr + t*8);
  f32x4 x1 = *(const f32x4*)(xr + t*8 + 4);
  f32x4 o0, o1;
  #pragma unroll
  for(int jq = 0; jq < 4; ++jq){
    o0[jq] = x0[jq] + fmaxf(fmaf(bf2f(hv[jq]), sc, sh), 0.f);
    o1[jq] = x1[jq] + fmaxf(fmaf(bf2f(hv[jq+4]), sc, sh), 0.f);
  }
  *(f32x4*)(orow + t*8) = o0;
  *(f32x4*)(orow + t*8 + 4) = o1;
}

extern "C" void kernel_launch(void* const* d_in, const int* in_sizes, int n_in,
                              void* d_out, int out_size, void* d_ws, size_t ws_size,
                              hipStream_t stream){
  const float* x     = (const float*)d_in[0];
  const float* Wq    = (const float*)d_in[1];
  const float* Wk    = (const float*)d_in[2];
  const float* Wv    = (const float*)d_in[3];
  const float* Wl    = (const float*)d_in[4];
  const float* gamma = (const float*)d_in[5];
  const float* beta  = (const float*)d_in[6];
  float* out = (float*)d_out;

  char* p = (char*)d_ws;
  double* xsum = (double*)p; p += (size_t)B_*C_*8;
  short* Wb   = (short*)p;  p += (size_t)384*C_*2;
  short* Wlf  = (short*)p;  p += (size_t)C_*C_*2;
  short* qbuf = (short*)p;  p += (size_t)B_*N_*64*2;
  short* kf   = (short*)p;  p += (size_t)B_*N_*64*2;
  short* vf   = (short*)p;  p += (size_t)B_*C_*N_*2;
  short* xTb  = (short*)p;  p += (size_t)B_*N_*C_*2;
  short* hT   = (short*)p;  p += (size_t)B_*N_*C_*2;
  float* part = (float*)p;  p += (size_t)512*512*4;
  float* part2= (float*)p;  p += (size_t)64*512*4;
  float* bnsc = (float*)p;  p += C_*4;
  float* bnsh = (float*)p;  p += C_*4;

  k_prep  <<<1408, 256, 0, stream>>>(Wq, Wk, Wv, Wl, Wb, Wlf, x, xsum);
  k_qkv   <<<dim3(N_/64, B_), 256, 0, stream>>>(x, Wb, xsum, Wq, Wk, qbuf, kf, vf, xTb);
  k_attn  <<<512, 256, 0, stream>>>(qbuf, kf, vf, xTb, Wlf, hT, part);
  k_bnred <<<64, 256, 0, stream>>>(part, part2);
  k_bnfin <<<1, 1024, 0, stream>>>(part2, gamma, beta, bnsc, bnsh);
  k_final <<<4096, 256, 0, stream>>>(x, hT, bnsc, bnsh, out);
}